// Round 14
// baseline (156.073 us; speedup 1.0000x reference)
//
#include <hip/hip_runtime.h>
#include <hip/hip_fp16.h>

// Tree NN: reps = emb[tokens] (4096 x 128 x 128); 7x: reps = tanh(concat(pairs) @ W_tree^T + b);
// out = root @ W_cls^T + b_cls.
//
// R14 = R13 (best: 83.5us/154.3us) + stale-row read clamping.
// Cycle audit of R13: per pair each wave reads ~320 distinct A-rows x 512 B from LDS;
// x12 waves/CU / 85 B/cyc (m134) ~ 90% LDS-read-pipe busy -- the hidden binding resource
// (MfmaUtil 20 / VALU 34 / HBM 19 all low; extra blocks never helped). Deep levels read
// mostly-garbage rows: L3 16 rows/8 valid, L4 16/4, L6 16/2. Clamp the read row to the
// valid range -> out-of-range lanes become same-address broadcasts (free, m136).
// Distinct rows/pair: 320 -> 254 (-21% LDS read bytes). No layout/register/barrier change.
//
// Wave w owns output n-tiles {2w,2w+1} at every level (Wf[2][8] = 64 VGPR of W-fragments).
// Activations in LDS, pair-contiguous so concat(left,right) is free. Per-sample phase-1
// gather,L0..L4 (stash L4-out in bufC); batched tail L5,L6+classifier per pair.
// Conflict-free gather (thread t -> row t&63, seg t>>6); token preload one section early.
// fp16 MFMA 16x16x32 (K-split 2 independent 4-chains), fp32 accumulate/tanh/classifier.

typedef _Float16 half8 __attribute__((ext_vector_type(8)));
typedef float floatx4 __attribute__((ext_vector_type(4)));

#define STRIDE 264   // 256 + 8 fp16 pad: A-row ds_read_b128 conflict-free
#define UROW   33    // uint4 per row
#define NPAIR  2048

__device__ __forceinline__ float fast_tanh(float x) {
  // No clamp needed: e=inf -> 1; e=0 -> -1. Inputs never NaN.
  float e = __expf(2.f * x);
  return 1.f - 2.f * __builtin_amdgcn_rcpf(e + 1.f);
}

__device__ __forceinline__ unsigned pkrtz(float a, float b) {
  auto h = __builtin_amdgcn_cvt_pkrtz(a, b);   // __fp16 ext_vector(2)
  return __builtin_bit_cast(unsigned, h);
}

// Gather: thread (row=t&63, seg=t>>6) covers leaf 2*row+(seg>>1), feature-half seg&1.
// 8 consecutive lanes hit 8 consecutive rows -> distinct bank-quads -> conflict-free.
__device__ __forceinline__ void gather_leafhalf(int tok, const float* __restrict__ emb,
                                                _Float16* buf, int row, int seg) {
  const float4* src = (const float4*)emb + (size_t)tok * 32 + (seg & 1) * 16;
  uint4* dst = (uint4*)buf + row * UROW + seg * 8;
#pragma unroll
  for (int j = 0; j < 8; ++j) {
    float4 x = src[2 * j], y = src[2 * j + 1];
    uint4 w;
    w.x = pkrtz(x.x, x.y); w.y = pkrtz(x.z, x.w);
    w.z = pkrtz(y.x, y.y); w.w = pkrtz(y.z, y.w);
    dst[j] = w;
  }
}

// K=256 MFMA for one 16-row m-tile, 2 n-tiles, K-split into 2 independent 4-chains.
// A-frag: A[m=lane&15][k=quad*8+j]; B-frag: B[k=quad*8+j][n=lane&15];
// D: col=lane&15, row=quad*4+reg (verified layouts, learn_hip m89/m91).
__device__ __forceinline__ void mfma_k256(const _Float16* arow, const half8 (&Wf)[2][8],
                                          floatx4 (&accO)[2]) {
  floatx4 aA[2], aB[2];
  aA[0] = (floatx4){0.f, 0.f, 0.f, 0.f}; aA[1] = (floatx4){0.f, 0.f, 0.f, 0.f};
  aB[0] = (floatx4){0.f, 0.f, 0.f, 0.f}; aB[1] = (floatx4){0.f, 0.f, 0.f, 0.f};
#pragma unroll
  for (int ks = 0; ks < 4; ++ks) {
    half8 x0 = *(const half8*)(arow + ks * 32);
    half8 x1 = *(const half8*)(arow + (ks + 4) * 32);
    aA[0] = __builtin_amdgcn_mfma_f32_16x16x32_f16(x0, Wf[0][ks],     aA[0], 0, 0, 0);
    aB[0] = __builtin_amdgcn_mfma_f32_16x16x32_f16(x1, Wf[0][ks + 4], aB[0], 0, 0, 0);
    aA[1] = __builtin_amdgcn_mfma_f32_16x16x32_f16(x0, Wf[1][ks],     aA[1], 0, 0, 0);
    aB[1] = __builtin_amdgcn_mfma_f32_16x16x32_f16(x1, Wf[1][ks + 4], aB[1], 0, 0, 0);
  }
  accO[0] = aA[0] + aB[0];
  accO[1] = aA[1] + aB[1];
}

// One wave: its 2 n-tiles for MT m-tiles; pair-contiguous store, MOUT row mask.
// RCLAMP (<15): max valid input row for MT=1 -- lanes above it read row RCLAMP
// (same-address broadcast, free) instead of stale rows (distinct, costly).
template<int MT, int MOUT, int RCLAMP>
__device__ __forceinline__ void level_std(
    const _Float16* inb, _Float16* outb,
    const half8 (&Wf)[2][8], const float (&bias)[2],
    int nbase, int l15, int quad)
{
  floatx4 acc[MT][2];
  if (MT == 1) {
    const int rr = (RCLAMP < 15) ? (l15 < RCLAMP ? l15 : RCLAMP) : l15;
    floatx4 a2[2];
    mfma_k256(inb + rr * STRIDE + quad * 8, Wf, a2);
    acc[0][0] = a2[0]; acc[0][1] = a2[1];
  } else {
#pragma unroll
    for (int m = 0; m < MT; ++m) {
      acc[m][0] = (floatx4){0.f, 0.f, 0.f, 0.f};
      acc[m][1] = (floatx4){0.f, 0.f, 0.f, 0.f};
    }
#pragma unroll
    for (int m = 0; m < MT; ++m) {
      const _Float16* arow = inb + (m * 16 + l15) * STRIDE + quad * 8;
#pragma unroll
      for (int ks = 0; ks < 8; ++ks) {
        half8 a = *(const half8*)(arow + ks * 32);
        acc[m][0] = __builtin_amdgcn_mfma_f32_16x16x32_f16(a, Wf[0][ks], acc[m][0], 0, 0, 0);
        acc[m][1] = __builtin_amdgcn_mfma_f32_16x16x32_f16(a, Wf[1][ks], acc[m][1], 0, 0, 0);
      }
    }
  }

  const int mrow = quad * 4;
#pragma unroll
  for (int m = 0; m < MT; ++m)
#pragma unroll
    for (int i = 0; i < 2; ++i) {
      const int col = (nbase + i) * 16 + l15;
#pragma unroll
      for (int r = 0; r < 4; ++r) {
        const int node = m * 16 + mrow + r;
        if (node < MOUT) {
          float v = fast_tanh(acc[m][i][r] + bias[i]);
          outb[(node >> 1) * STRIDE + (node & 1) * 128 + col] = (_Float16)v;
        }
      }
    }
}

__global__ __launch_bounds__(256, 3)   // proven config: cap 80 >= demand ~76, 3 blocks/CU
void tree_kernel(const int* __restrict__ tokens,
                 const float* __restrict__ embedding,
                 const float* __restrict__ W_tree,
                 const float* __restrict__ b_tree,
                 const float* __restrict__ W_cls,
                 const float* __restrict__ b_cls,
                 float* __restrict__ out)
{
  __shared__ __align__(16) _Float16 bufA[64 * STRIDE];   // leaves / even outputs (33.8 KB)
  __shared__ __align__(16) _Float16 bufB[32 * STRIDE];   // odd outputs (16.9 KB)
  __shared__ __align__(16) _Float16 bufC[4 * STRIDE];    // pair stash: L4 outs (2.1 KB)
  __shared__ float wavepart[4][2][3];                    // classifier partials (96 B)

  const int tid  = threadIdx.x;
  const int wid  = tid >> 6;
  const int lane = tid & 63;
  const int l15  = lane & 15;
  const int quad = lane >> 4;
  const int nbase = wid * 2;               // this wave's n-tile base (features [32*wid,32*wid+32))
  const int row  = tid & 63;               // gather destination row
  const int seg  = tid >> 6;               // gather leaf-half / feature-half segment
  const int tidx = 2 * row + (seg >> 1);   // this thread's token index within a sample

  // ---- stage this wave's 2 n-tiles of W_tree as B-fragments (64 VGPR) ----
  // B[k][n] = W_tree[e=n][h=k]  (einsum 'bnh,eh->bne' => out = comb @ W^T)
  half8 Wf[2][8];
#pragma unroll
  for (int i = 0; i < 2; ++i) {
    const int e = (nbase + i) * 16 + l15;
#pragma unroll
    for (int ks = 0; ks < 8; ++ks) {
      const int k = ks * 32 + quad * 8;
      const float4* p = (const float4*)(W_tree + e * 256 + k);
      float4 lo = p[0], hi = p[1];
      half8 f;
      f[0] = (_Float16)lo.x; f[1] = (_Float16)lo.y; f[2] = (_Float16)lo.z; f[3] = (_Float16)lo.w;
      f[4] = (_Float16)hi.x; f[5] = (_Float16)hi.y; f[6] = (_Float16)hi.z; f[7] = (_Float16)hi.w;
      Wf[i][ks] = f;
    }
  }
  float bias[2];
#pragma unroll
  for (int i = 0; i < 2; ++i) bias[i] = b_tree[(nbase + i) * 16 + l15];

  // classifier weights for this lane's 2 columns: loop-invariant (6 VGPR)
  float wc[2][3];
#pragma unroll
  for (int i = 0; i < 2; ++i) {
    const int col = (nbase + i) * 16 + l15;
#pragma unroll
    for (int o = 0; o < 3; ++o) wc[i][o] = W_cls[o * 128 + col];
  }

  int tokA = tokens[(2 * blockIdx.x) * 128 + tidx];   // preloaded s0 token (first pair)

#pragma unroll 1
  for (int p = blockIdx.x; p < NPAIR; p += gridDim.x) {
    int pn = p + gridDim.x;
    if (pn >= NPAIR) pn = p;               // last iteration: harmless self-reload

    // ---- s0 gather (token preloaded) + preload s1 token ----
    gather_leafhalf(tokA, embedding, bufA, row, seg);
    const int tokB = tokens[(2 * p + 1) * 128 + tidx];
    __syncthreads();

    // ---- s0 levels: L0..L4, stash L4-out in bufC rows 0-1 ----
    level_std<4, 64, 15>(bufA, bufB, Wf, bias, nbase, l15, quad);   // L0
    __syncthreads();
    level_std<2, 32, 15>(bufB, bufA, Wf, bias, nbase, l15, quad);   // L1
    __syncthreads();
    level_std<1, 16, 15>(bufA, bufB, Wf, bias, nbase, l15, quad);   // L2: 16 valid rows
    __syncthreads();
    level_std<1,  8,  7>(bufB, bufA, Wf, bias, nbase, l15, quad);   // L3: rows 0-7 valid
    __syncthreads();
    level_std<1,  4,  3>(bufA, bufC, Wf, bias, nbase, l15, quad);   // L4: rows 0-3 valid
    __syncthreads();

    // ---- s1 gather (token preloaded) + preload next-pair s0 token ----
    gather_leafhalf(tokB, embedding, bufA, row, seg);
    tokA = tokens[(2 * pn) * 128 + tidx];
    __syncthreads();

    // ---- s1 levels: L0..L4, stash L4-out in bufC rows 2-3 ----
    level_std<4, 64, 15>(bufA, bufB, Wf, bias, nbase, l15, quad);   // L0
    __syncthreads();
    level_std<2, 32, 15>(bufB, bufA, Wf, bias, nbase, l15, quad);   // L1
    __syncthreads();
    level_std<1, 16, 15>(bufA, bufB, Wf, bias, nbase, l15, quad);   // L2
    __syncthreads();
    level_std<1,  8,  7>(bufB, bufA, Wf, bias, nbase, l15, quad);   // L3
    __syncthreads();
    level_std<1,  4,  3>(bufA, bufC + 2 * STRIDE, Wf, bias, nbase, l15, quad); // L4
    __syncthreads();

    // ---- batched L5: bufC rows 0-3 -> bufA rows 0-1 ----
    {
      const int rclamp = l15 < 4 ? l15 : 3;          // bufC bounds; rows>=4 discarded
      floatx4 acc[2];
      mfma_k256(bufC + rclamp * STRIDE + quad * 8, Wf, acc);
      const int mrow = quad * 4;
#pragma unroll
      for (int i = 0; i < 2; ++i) {
        const int col = (nbase + i) * 16 + l15;
#pragma unroll
        for (int r = 0; r < 4; ++r) {
          const int mr = mrow + r;                   // mr<4 valid: sample mr>>1, node mr&1
          if (mr < 4) {
            float v = fast_tanh(acc[i][r] + bias[i]);
            bufA[(mr >> 1) * STRIDE + (mr & 1) * 128 + col] = (_Float16)v;
          }
        }
      }
    }
    __syncthreads();

    // ---- batched L6 + classifier partials from registers ----
    {
      const int rclamp = l15 < 2 ? l15 : 1;          // rows 0-1 valid = roots s0,s1
      floatx4 acc[2];
      mfma_k256(bufA + rclamp * STRIDE + quad * 8, Wf, acc);
      float part[2][3] = {{0.f, 0.f, 0.f}, {0.f, 0.f, 0.f}};
      if (quad == 0) {
#pragma unroll
        for (int i = 0; i < 2; ++i) {
#pragma unroll
          for (int rr = 0; rr < 2; ++rr) {           // rr = sample
            float v = fast_tanh(acc[i][rr] + bias[i]);
#pragma unroll
            for (int o = 0; o < 3; ++o) part[rr][o] = fmaf(v, wc[i][o], part[rr][o]);
          }
        }
      }
#pragma unroll
      for (int rr = 0; rr < 2; ++rr) {
#pragma unroll
        for (int o = 0; o < 3; ++o) {
          float v = part[rr][o];                     // nonzero only in quad-0 lanes
          v += __shfl_down(v, 8);
          v += __shfl_down(v, 4);
          v += __shfl_down(v, 2);
          v += __shfl_down(v, 1);
          if (lane == 0) wavepart[wid][rr][o] = v;
        }
      }
    }
    __syncthreads();
    if (tid < 6) {
      const int rr = tid / 3, o = tid - 3 * rr;
      float v = wavepart[0][rr][o] + wavepart[1][rr][o]
              + wavepart[2][rr][o] + wavepart[3][rr][o];
      out[(2 * p + rr) * 3 + o] = v + b_cls[o];
    }
    // next pair's gather overwrites bufA: all L6 bufA reads completed before the wavepart
    // barrier; wavepart next written 13 barriers later -> safe.
  }
}

extern "C" void kernel_launch(void* const* d_in, const int* in_sizes, int n_in,
                              void* d_out, int out_size, void* d_ws, size_t ws_size,
                              hipStream_t stream) {
  const int*   tokens    = (const int*)d_in[0];
  const float* embedding = (const float*)d_in[1];
  const float* W_tree    = (const float*)d_in[2];
  const float* b_tree    = (const float*)d_in[3];
  const float* W_cls     = (const float*)d_in[4];
  const float* b_cls     = (const float*)d_in[5];
  float* out = (float*)d_out;

  dim3 grid(768), block(256);   // 3 blocks/CU x 256 CUs; grid-stride over 2048 pairs
  tree_kernel<<<grid, block, 0, stream>>>(tokens, embedding, W_tree, b_tree, W_cls, b_cls, out);
}